// Round 11
// baseline (331.423 us; speedup 1.0000x reference)
//
#include <hip/hip_runtime.h>
#include <hip/hip_bf16.h>

#define EPSV 1e-5f
#define CHUNK 256   // dst nodes per bucket (bucket = dst >> 8)
#define CAP 6144    // slots per bucket (mean 4096, +16 sigma + padding)
#define MAXNB 512   // supports N <= 131072
#define EPB 4096    // edges per block in bucket_scatter

typedef __attribute__((ext_vector_type(8))) short bf16x8;
typedef __attribute__((ext_vector_type(4))) float f32x4;

__device__ __forceinline__ ushort f2bf(float f) {
    union { float f; unsigned u; } c; c.f = f;
    unsigned u = c.u;
    return (ushort)((u + 0x7fffu + ((u >> 16) & 1u)) >> 16);
}
__device__ __forceinline__ float bf2f(ushort h) {
    union { unsigned u; float f; } c; c.u = ((unsigned)h) << 16;
    return c.f;
}
__device__ __forceinline__ float bflo(unsigned u) {
    union { unsigned u; float f; } c; c.u = u << 16;
    return c.f;
}
__device__ __forceinline__ float bfhi(unsigned u) {
    union { unsigned u; float f; } c; c.u = u & 0xFFFF0000u;
    return c.f;
}
// int8 row decode-accumulate: a[f] += sc * q[f]  (q packed 8x int8 in uint2)
__device__ __forceinline__ void accq(float* a, uint2 g, float sc) {
    a[0] += sc * (float)(signed char)(g.x & 0xFF);
    a[1] += sc * (float)(signed char)((g.x >> 8) & 0xFF);
    a[2] += sc * (float)(signed char)((g.x >> 16) & 0xFF);
    a[3] += sc * (float)(signed char)(g.x >> 24);
    a[4] += sc * (float)(signed char)(g.y & 0xFF);
    a[5] += sc * (float)(signed char)((g.y >> 8) & 0xFF);
    a[6] += sc * (float)(signed char)((g.y >> 16) & 0xFF);
    a[7] += sc * (float)(signed char)(g.y >> 24);
}

// ---------- prep: W swizzle + zeroing (deg[N] + zero region + table zero-row) ----------
// W (k,n) -> wsw[((k>>3)*64 + n)*8 + (k&7)]
// Zeroed EVERY launch (re-poison safe). Grid 128x256=32768 threads covers nz16 (~25.3K).

__global__ void prep_kernel(const float* __restrict__ W1, const float* __restrict__ W2,
                            ushort* __restrict__ wsw1, ushort* __restrict__ wsw2,
                            uint4* __restrict__ zr, int nz16, char* __restrict__ T8,
                            float* __restrict__ scales16, int N) {
    int t = blockIdx.x * blockDim.x + threadIdx.x;
    if (t < 128 * 64) {
        int k = t >> 6, n = t & 63;
        wsw1[((k >> 3) * 64 + n) * 8 + (k & 7)] = f2bf(W1[t]);
    }
    if (t < 64 * 64) {
        int k = t >> 6, n = t & 63;
        wsw2[((k >> 3) * 64 + n) * 8 + (k & 7)] = f2bf(W2[t]);
    }
    if (t < nz16) zr[t] = make_uint4(0u, 0u, 0u, 0u);
    if (t < 4) reinterpret_cast<uint4*>(T8 + (size_t)N * 64)[t] = make_uint4(0u, 0u, 0u, 0u);
    if (t == 4) scales16[N >> 4] = 0.f;  // zero-row group scale (overwritten by mm if shared)
}

// ---------- bucket scatter: pack (src | dloc<<20) into fixed-cap bucket regions ----------
// R3 lesson: single-pass scatter into per-node slots costs 97MB of HBM writes (64B-line
// amplification). Bucket cursors fill lines sequentially. bcur RELATIVE (zeroed by prep).
// v2: hist pass ALSO accumulates global deg[N] (fire-and-forget atomics on loaded dst)
// so bucket_finish can skip its entire histogram pass.

__global__ void __launch_bounds__(256) bucket_scatter(const int* __restrict__ ei,
                                                      int* __restrict__ bcur,
                                                      unsigned* __restrict__ bdata,
                                                      int* __restrict__ deg, int E,
                                                      int NB) {
    __shared__ int h[MAXNB];
    __shared__ int cur[MAXNB];
    int t = threadIdx.x;
    int base = blockIdx.x * EPB;
    int end = min(base + EPB, E);
    for (int b = t; b < NB; b += 256) h[b] = 0;
    __syncthreads();
    // hist pass (int4 over dst; E and EPB divisible by 4) + global degree
    for (int e = base + t * 4; e < end; e += 1024) {
        int4 d4 = *reinterpret_cast<const int4*>(&ei[E + e]);
        atomicAdd(&h[d4.x >> 8], 1);
        atomicAdd(&h[d4.y >> 8], 1);
        atomicAdd(&h[d4.z >> 8], 1);
        atomicAdd(&h[d4.w >> 8], 1);
        atomicAdd(&deg[d4.x], 1);
        atomicAdd(&deg[d4.y], 1);
        atomicAdd(&deg[d4.z], 1);
        atomicAdd(&deg[d4.w], 1);
    }
    __syncthreads();
    for (int b = t; b < NB; b += 256) {
        int c = h[b];
        cur[b] = c ? (atomicAdd(&bcur[b], c) + b * CAP) : 0;
    }
    __syncthreads();
    for (int e = base + t * 4; e < end; e += 1024) {
        int4 s4 = *reinterpret_cast<const int4*>(&ei[e]);
        int4 d4 = *reinterpret_cast<const int4*>(&ei[E + e]);
        int p0 = atomicAdd(&cur[d4.x >> 8], 1);
        bdata[p0] = (unsigned)s4.x | ((unsigned)(d4.x & 255) << 20);
        int p1 = atomicAdd(&cur[d4.y >> 8], 1);
        bdata[p1] = (unsigned)s4.y | ((unsigned)(d4.y & 255) << 20);
        int p2 = atomicAdd(&cur[d4.z >> 8], 1);
        bdata[p2] = (unsigned)s4.z | ((unsigned)(d4.z & 255) << 20);
        int p3 = atomicAdd(&cur[d4.w >> 8], 1);
        bdata[p3] = (unsigned)s4.w | ((unsigned)(d4.w & 255) << 20);
    }
}

// ---------- bucket finish v2: NO hist pass (deg from global) -> scan -> scatter -> pad ----
// Removes one full 6.4MB bdata read + 1.6M LDS atomics + a barrier round vs v1.
// Place pass reads bdata as int4 (4x fewer load instructions). srcs holds src*8;
// lists padded to x4 with ZR (= N*8) entries.

__global__ void __launch_bounds__(256) bucket_finish(const unsigned* __restrict__ bdata,
                                                     const int* __restrict__ bcur,
                                                     const int* __restrict__ deg,
                                                     int2* __restrict__ NI,
                                                     float* __restrict__ dinv,
                                                     int* __restrict__ srcs, int N) {
    __shared__ int h[CHUNK];
    __shared__ int cur[CHUNK];
    int t = threadIdx.x;
    int beg = blockIdx.x * CAP;
    int node = blockIdx.x * CHUNK + t;
    int dg = (node < N) ? deg[node] : 0;
    int pc = (dg + 3) & ~3;
    cur[t] = pc;
    __syncthreads();
    for (int off = 1; off < 256; off <<= 1) {
        int x = (t >= off) ? cur[t - off] : 0;
        __syncthreads();
        cur[t] += x;
        __syncthreads();
    }
    int begp = beg + cur[t] - pc;  // padded start for this node's list
    if (node < N) {
        NI[node] = make_int2(begp, pc);
        dinv[node] = rsqrtf((float)dg + 1.0f);
    }
    h[t] = begp;
    __syncthreads();
    int end = beg + bcur[blockIdx.x];  // bcur is relative count
    int end4 = beg + ((end - beg) & ~3);
    for (int e = beg + t * 4; e < end4; e += 1024) {
        uint4 p4 = *reinterpret_cast<const uint4*>(&bdata[e]);
        int pos0 = atomicAdd(&h[p4.x >> 20], 1);
        srcs[pos0] = (int)((p4.x & 0xFFFFFu) << 3);  // src * 8 (uint2 row offset)
        int pos1 = atomicAdd(&h[p4.y >> 20], 1);
        srcs[pos1] = (int)((p4.y & 0xFFFFFu) << 3);
        int pos2 = atomicAdd(&h[p4.z >> 20], 1);
        srcs[pos2] = (int)((p4.z & 0xFFFFFu) << 3);
        int pos3 = atomicAdd(&h[p4.w >> 20], 1);
        srcs[pos3] = (int)((p4.w & 0xFFFFFu) << 3);
    }
    if (t < end - end4) {  // scalar tail (<4 entries)
        unsigned p = bdata[end4 + t];
        int pos = atomicAdd(&h[p >> 20], 1);
        srcs[pos] = (int)((p & 0xFFFFFu) << 3);
    }
    __syncthreads();
    // pad fill: h[t] is now begp+deg
    int zr = N * 8;
    for (int k = h[t]; k < begp + pc; k++) srcs[k] = zr;
}

// ---------- int8 quantize epilogue (shared by mm1/mm2), PER-16-ROW scale ----------
// A warp covers exactly rows [gw*16, gw*16+16): one full-wave max reduce gives the
// group scale. scales16 = 25KB total (R9-verified numerics, absmax 0.03125 passed).

__device__ __forceinline__ void quant_store(const f32x4* accs, const float* dv, int rbase,
                                            int ml, int gw, char* __restrict__ T8,
                                            float* __restrict__ scales16, int N) {
    float m = 0.f;
#pragma unroll
    for (int reg = 0; reg < 4; reg++) {
        float mr = fmaxf(fmaxf(fabsf(accs[0][reg]), fabsf(accs[1][reg])),
                         fmaxf(fabsf(accs[2][reg]), fabsf(accs[3][reg])));
        m = fmaxf(m, mr * dv[reg]);  // dv=0 for masked rows -> no contribution
    }
    m = fmaxf(m, __shfl_xor(m, 1));
    m = fmaxf(m, __shfl_xor(m, 2));
    m = fmaxf(m, __shfl_xor(m, 4));
    m = fmaxf(m, __shfl_xor(m, 8));
    m = fmaxf(m, __shfl_xor(m, 16));
    m = fmaxf(m, __shfl_xor(m, 32));
    m = fmaxf(m, 1e-20f);
    float inv = 127.f / m;
    if ((threadIdx.x & 63) == 0) scales16[gw] = m * (1.f / 127.f);
#pragma unroll
    for (int reg = 0; reg < 4; reg++) {
        int r = rbase + reg;
        if (r < N) {
            float s = dv[reg] * inv;
#pragma unroll
            for (int ct = 0; ct < 4; ct++) {
                int qv = __float2int_rn(accs[ct][reg] * s);
                T8[(size_t)r * 64 + ct * 16 + ml] = (char)qv;
            }
        }
    }
}

// ---------- matmul1: T8[N,64](int8)+scales16 = quant(dinv[r] * (X[N,128](fp32) @ W1)) ----------

__global__ void __launch_bounds__(256) mm1_kernel(const float* __restrict__ X,
                                                  const ushort* __restrict__ wsw,
                                                  const float* __restrict__ dinv,
                                                  char* __restrict__ T8,
                                                  float* __restrict__ scales16, int N) {
    const int KO = 4;
    int w = threadIdx.x >> 6, lane = threadIdx.x & 63;
    int ml = lane & 15, q = lane >> 4;
    int row = blockIdx.x * 64 + w * 16 + ml;

    bf16x8 afrag[KO];
#pragma unroll
    for (int kk = 0; kk < KO; kk++) {
        float xv[8];
        if (row < N) {
            const float4* xp = reinterpret_cast<const float4*>(X + (size_t)row * 128 + kk * 32 + q * 8);
            float4 v0 = xp[0], v1 = xp[1];
            xv[0] = v0.x; xv[1] = v0.y; xv[2] = v0.z; xv[3] = v0.w;
            xv[4] = v1.x; xv[5] = v1.y; xv[6] = v1.z; xv[7] = v1.w;
        } else {
#pragma unroll
            for (int j = 0; j < 8; j++) xv[j] = 0.f;
        }
#pragma unroll
        for (int j = 0; j < 8; j++) afrag[kk][j] = (short)f2bf(xv[j]);
    }

    int rbase = blockIdx.x * 64 + w * 16 + q * 4;
    float dv[4];
#pragma unroll
    for (int reg = 0; reg < 4; reg++) {
        int r = rbase + reg;
        dv[reg] = (r < N) ? dinv[r] : 0.f;
    }

    const bf16x8* wp = reinterpret_cast<const bf16x8*>(wsw);
    f32x4 accs[4];
#pragma unroll
    for (int ct = 0; ct < 4; ct++) {
        f32x4 acc = {0.f, 0.f, 0.f, 0.f};
#pragma unroll
        for (int kk = 0; kk < KO; kk++) {
            bf16x8 b = wp[(kk * 4 + q) * 64 + ct * 16 + ml];
            acc = __builtin_amdgcn_mfma_f32_16x16x32_bf16(afrag[kk], b, acc, 0, 0, 0);
        }
        accs[ct] = acc;
    }
    quant_store(accs, dv, rbase, ml, blockIdx.x * 4 + w, T8, scales16, N);
}

// ---------- matmul2: fused GraphNorm+LayerNorm on A, then T8 = quant(dinv * (norm(A) @ W2)) ----------

__global__ void __launch_bounds__(256) mm2_kernel(
    const ushort* __restrict__ A2, const ushort* __restrict__ wsw,
    const float* __restrict__ sums, const float* __restrict__ gn_w,
    const float* __restrict__ gn_b, const float* __restrict__ gn_ms,
    const float* __restrict__ ln_w, const float* __restrict__ ln_b,
    const float* __restrict__ dinv, char* __restrict__ T8,
    float* __restrict__ scales16, int N) {
    __shared__ float sg[64], tg[64], lwv[64], lbv[64];
    int t = threadIdx.x;
    if (t < 64) {
        float invN = 1.0f / (float)N;
        float mean = sums[t] * invN;
        float m2 = sums[64 + t] * invN;
        float ms = gn_ms[t];
        float var = m2 - 2.f * ms * mean * mean + ms * ms * mean * mean;
        float s = gn_w[t] * rsqrtf(var + EPSV);
        sg[t] = s;
        tg[t] = gn_b[t] - s * ms * mean;
        lwv[t] = ln_w[t];
        lbv[t] = ln_b[t];
    }
    __syncthreads();

    int w = t >> 6, lane = t & 63;
    int ml = lane & 15, q = lane >> 4;
    int row = blockIdx.x * 64 + w * 16 + ml;

    float g[16];
#pragma unroll
    for (int kk = 0; kk < 2; kk++) {
        uint4 u = make_uint4(0, 0, 0, 0);
        if (row < N)
            u = *reinterpret_cast<const uint4*>(A2 + (size_t)row * 64 + kk * 32 + q * 8);
        unsigned uu[4] = {u.x, u.y, u.z, u.w};
#pragma unroll
        for (int p = 0; p < 4; p++) {
            int f0 = kk * 32 + q * 8 + 2 * p;
            g[kk * 8 + 2 * p] = sg[f0] * bflo(uu[p]) + tg[f0];
            g[kk * 8 + 2 * p + 1] = sg[f0 + 1] * bfhi(uu[p]) + tg[f0 + 1];
        }
    }
    float s1 = 0.f;
#pragma unroll
    for (int i = 0; i < 16; i++) s1 += g[i];
    s1 += __shfl_xor(s1, 16);
    s1 += __shfl_xor(s1, 32);
    float mu = s1 * (1.f / 64.f);
    float s2 = 0.f;
#pragma unroll
    for (int i = 0; i < 16; i++) {
        float c = g[i] - mu;
        s2 += c * c;
    }
    s2 += __shfl_xor(s2, 16);
    s2 += __shfl_xor(s2, 32);
    float rs = rsqrtf(s2 * (1.f / 64.f) + EPSV);

    bf16x8 afrag[2];
#pragma unroll
    for (int kk = 0; kk < 2; kk++) {
#pragma unroll
        for (int j = 0; j < 8; j++) {
            int f = kk * 32 + q * 8 + j;
            float y = lwv[f] * (g[kk * 8 + j] - mu) * rs + lbv[f];
            afrag[kk][j] = (short)f2bf(y);
        }
    }

    int rbase = blockIdx.x * 64 + w * 16 + q * 4;
    float dv[4];
#pragma unroll
    for (int reg = 0; reg < 4; reg++) {
        int r = rbase + reg;
        dv[reg] = (r < N) ? dinv[r] : 0.f;
    }

    const bf16x8* wp = reinterpret_cast<const bf16x8*>(wsw);
    f32x4 accs[4];
#pragma unroll
    for (int ct = 0; ct < 4; ct++) {
        f32x4 acc = {0.f, 0.f, 0.f, 0.f};
#pragma unroll
        for (int kk = 0; kk < 2; kk++) {
            bf16x8 b = wp[(kk * 4 + q) * 64 + ct * 16 + ml];
            acc = __builtin_amdgcn_mfma_f32_16x16x32_bf16(afrag[kk], b, acc, 0, 0, 0);
        }
        accs[ct] = acc;
    }
    quant_store(accs, dv, rbase, ml, blockIdx.x * 4 + w, T8, scales16, N);
}

// ---------- edge aggregation v12 (FINAL): int8 table + LDS-staged scales ----------
// agg is at the random-gather serve-rate ceiling (~34G line-requests/s chip-wide):
// five falsified theories — more waves (R1), deeper pipeline (R2), fewer bytes (R8),
// fewer misses (R9), fewer L1 txns (R10: -1.6us only). Do not touch further.

__global__ void __launch_bounds__(256) agg_kernel(
    const char* __restrict__ T8, const float* __restrict__ scales16,
    const int2* __restrict__ NI, const int* __restrict__ srcs,
    const float* __restrict__ dinv, const float* __restrict__ bias,
    ushort* __restrict__ out, float* __restrict__ sums, int N) {
    extern __shared__ float sc[];  // (N>>4)+1 floats, dynamic
    int t = threadIdx.x;
    int nsc = (N >> 4) + 1;
    for (int i = t; i < nsc; i += 256) sc[i] = scales16[i];
    __syncthreads();

    int lane = t & 63;
    int g = lane >> 3, fq = lane & 7;
    int wid = (blockIdx.x * blockDim.x + t) >> 6;
    int nw = (gridDim.x * blockDim.x) >> 6;
    const uint2* H2 = reinterpret_cast<const uint2*>(T8);
    uint4* O4 = reinterpret_cast<uint4*>(out);
    const int ZR = N * 8;
    float bb[8];
#pragma unroll
    for (int j = 0; j < 8; j++) bb[j] = bias[fq * 8 + j];
    float ps1[8] = {0, 0, 0, 0, 0, 0, 0, 0}, ps2[8] = {0, 0, 0, 0, 0, 0, 0, 0};

    for (int jo = wid; jo * 8 < N; jo += nw) {
        int node = jo * 8 + g;
        bool valid = node < N;
        int2 info = valid ? NI[node] : make_int2(0, 0);
        float di = valid ? dinv[node] : 0.f;
        int e = info.x, end = info.x + info.y;
        float a[8] = {0, 0, 0, 0, 0, 0, 0, 0};
        for (; e + 8 <= end; e += 8) {
            int4 i0 = *reinterpret_cast<const int4*>(&srcs[e]);
            int4 i1 = *reinterpret_cast<const int4*>(&srcs[e + 4]);
            uint2 g0 = H2[i0.x + fq];
            uint2 g1 = H2[i0.y + fq];
            uint2 g2 = H2[i0.z + fq];
            uint2 g3 = H2[i0.w + fq];
            uint2 g4 = H2[i1.x + fq];
            uint2 g5 = H2[i1.y + fq];
            uint2 g6 = H2[i1.z + fq];
            uint2 g7 = H2[i1.w + fq];
            float s0 = sc[i0.x >> 7];   // (src*8)>>7 = src>>4 ; LDS, not L1
            float s1 = sc[i0.y >> 7];
            float s2 = sc[i0.z >> 7];
            float s3 = sc[i0.w >> 7];
            float s4 = sc[i1.x >> 7];
            float s5 = sc[i1.y >> 7];
            float s6 = sc[i1.z >> 7];
            float s7 = sc[i1.w >> 7];
            accq(a, g0, s0); accq(a, g1, s1); accq(a, g2, s2); accq(a, g3, s3);
            accq(a, g4, s4); accq(a, g5, s5); accq(a, g6, s6); accq(a, g7, s7);
        }
        if (e < end) {  // remainder is exactly 4 (lists padded to x4)
            int4 i0 = *reinterpret_cast<const int4*>(&srcs[e]);
            uint2 g0 = H2[i0.x + fq];
            uint2 g1 = H2[i0.y + fq];
            uint2 g2 = H2[i0.z + fq];
            uint2 g3 = H2[i0.w + fq];
            float s0 = sc[i0.x >> 7];
            float s1 = sc[i0.y >> 7];
            float s2 = sc[i0.z >> 7];
            float s3 = sc[i0.w >> 7];
            accq(a, g0, s0); accq(a, g1, s1); accq(a, g2, s2); accq(a, g3, s3);
        }
        // self term: same di coefficient as neighbors -> fold into a[]
        uint2 us = H2[(valid ? node * 8 : ZR) + fq];
        float scs = sc[(valid ? node : N) >> 4];
        accq(a, us, scs);
        float vv[8];
#pragma unroll
        for (int j = 0; j < 8; j++) vv[j] = fmaxf(di * a[j] + bb[j], 0.f);
        if (valid) {
            uint4 o;
            o.x = (unsigned)f2bf(vv[0]) | ((unsigned)f2bf(vv[1]) << 16);
            o.y = (unsigned)f2bf(vv[2]) | ((unsigned)f2bf(vv[3]) << 16);
            o.z = (unsigned)f2bf(vv[4]) | ((unsigned)f2bf(vv[5]) << 16);
            o.w = (unsigned)f2bf(vv[6]) | ((unsigned)f2bf(vv[7]) << 16);
            O4[(size_t)node * 8 + fq] = o;
#pragma unroll
            for (int j = 0; j < 8; j++) {
                ps1[j] += vv[j];
                ps2[j] += vv[j] * vv[j];
            }
        }
    }

    // colstats: reduce across the 8 groups (same fq -> same features), stage in LDS
    __shared__ float red[4][128];
    int wv = t >> 6;
#pragma unroll
    for (int j = 0; j < 8; j++) {
        float s = ps1[j], q = ps2[j];
        s += __shfl_xor(s, 8); s += __shfl_xor(s, 16); s += __shfl_xor(s, 32);
        q += __shfl_xor(q, 8); q += __shfl_xor(q, 16); q += __shfl_xor(q, 32);
        if (g == 0) {
            red[wv][fq * 8 + j] = s;
            red[wv][64 + fq * 8 + j] = q;
        }
    }
    __syncthreads();
    if (t < 128) {
        float v = red[0][t] + red[1][t] + red[2][t] + red[3][t];
        atomicAdd(&sums[t], v);
    }
}

// ---------- layer-2 norms + max-pool + (last block) final FC ----------
// 8x8 layout (R5-verified): lane fq loads uint4 (8 features) of row jo*8+g; wave reads
// 1KB coalesced covering 8 rows/iter; LN reductions are 3-hop shfl within 8-lane group.

__device__ __forceinline__ unsigned fkey(float f) {
    unsigned u = __float_as_uint(f);
    return (u & 0x80000000u) ? ~u : (u | 0x80000000u);
}

__global__ void __launch_bounds__(256) gnlnmax_final(
    const ushort* __restrict__ A, const float* __restrict__ sums,
    const float* __restrict__ gn_w, const float* __restrict__ gn_b,
    const float* __restrict__ gn_ms, const float* __restrict__ ln_w,
    const float* __restrict__ ln_b, unsigned* __restrict__ pooled,
    unsigned* __restrict__ done, const float* __restrict__ fc_W,
    const float* __restrict__ fc_b, float* __restrict__ out, int N) {
    __shared__ float sg[64], tg[64];
    int t = threadIdx.x;
    if (t < 64) {
        float invN = 1.0f / (float)N;
        float mean = sums[t] * invN;
        float m2 = sums[64 + t] * invN;
        float ms = gn_ms[t];
        float var = m2 - 2.f * ms * mean * mean + ms * ms * mean * mean;
        float s = gn_w[t] * rsqrtf(var + EPSV);
        sg[t] = s;
        tg[t] = gn_b[t] - s * ms * mean;
    }
    __syncthreads();

    int lane = t & 63;
    int g = lane >> 3, fq = lane & 7;
    float sgv[8], tgv[8], lwv[8], lbv[8];
#pragma unroll
    for (int j = 0; j < 8; j++) {
        sgv[j] = sg[fq * 8 + j];
        tgv[j] = tg[fq * 8 + j];
        lwv[j] = ln_w[fq * 8 + j];
        lbv[j] = ln_b[fq * 8 + j];
    }

    int wid = (blockIdx.x * blockDim.x + t) >> 6;
    int nw = (gridDim.x * blockDim.x) >> 6;
    const uint4* A4 = reinterpret_cast<const uint4*>(A);
    float mx[8];
#pragma unroll
    for (int j = 0; j < 8; j++) mx[j] = -3.4e38f;

    for (int jo = wid; jo * 8 < N; jo += nw) {
        int row = jo * 8 + g;
        bool valid = row < N;
        uint4 u = A4[(size_t)(valid ? row : 0) * 8 + fq];
        float y[8];
        y[0] = sgv[0] * bflo(u.x) + tgv[0];
        y[1] = sgv[1] * bfhi(u.x) + tgv[1];
        y[2] = sgv[2] * bflo(u.y) + tgv[2];
        y[3] = sgv[3] * bfhi(u.y) + tgv[3];
        y[4] = sgv[4] * bflo(u.z) + tgv[4];
        y[5] = sgv[5] * bfhi(u.z) + tgv[5];
        y[6] = sgv[6] * bflo(u.w) + tgv[6];
        y[7] = sgv[7] * bfhi(u.w) + tgv[7];
        float s1 = 0.f;
#pragma unroll
        for (int j = 0; j < 8; j++) s1 += y[j];
        s1 += __shfl_xor(s1, 1);
        s1 += __shfl_xor(s1, 2);
        s1 += __shfl_xor(s1, 4);
        float mu = s1 * (1.f / 64.f);
        float s2 = 0.f;
#pragma unroll
        for (int j = 0; j < 8; j++) {
            float c = y[j] - mu;
            s2 += c * c;
        }
        s2 += __shfl_xor(s2, 1);
        s2 += __shfl_xor(s2, 2);
        s2 += __shfl_xor(s2, 4);
        float rs = rsqrtf(s2 * (1.f / 64.f) + EPSV);
        if (valid) {
#pragma unroll
            for (int j = 0; j < 8; j++)
                mx[j] = fmaxf(mx[j], lwv[j] * (y[j] - mu) * rs + lbv[j]);
        }
    }

    // reduce max across the 8 groups (same fq -> same features), stage in LDS
    __shared__ float red[4][64];
    int wv = t >> 6;
#pragma unroll
    for (int j = 0; j < 8; j++) {
        float m = mx[j];
        m = fmaxf(m, __shfl_xor(m, 8));
        m = fmaxf(m, __shfl_xor(m, 16));
        m = fmaxf(m, __shfl_xor(m, 32));
        if (g == 0) red[wv][fq * 8 + j] = m;
    }
    __syncthreads();
    if (t < 64) {
        float m = fmaxf(fmaxf(red[0][t], red[1][t]), fmaxf(red[2][t], red[3][t]));
        atomicMax(&pooled[t], fkey(m));
    }
    __syncthreads();  // all this block's atomicMax issued before the counter bump
    __shared__ int islast;
    if (t == 0) {
        __threadfence();  // publish our maxes
        unsigned old = atomicAdd(done, 1u);
        islast = (old == gridDim.x - 1);
    }
    __syncthreads();
    if (islast) {  // every other block fenced+counted -> their maxes are visible
        __shared__ float p[64];
        if (t < 64) {
            __threadfence();
            unsigned u = atomicAdd(&pooled[t], 0u);  // atomic RMW read bypasses stale caches
            p[t] = (u & 0x80000000u) ? __uint_as_float(u ^ 0x80000000u) : __uint_as_float(~u);
        }
        __syncthreads();
        if (t < 32) {
            float acc = fc_b[t];
#pragma unroll
            for (int f = 0; f < 64; f++) acc += p[f] * fc_W[f * 32 + t];
            out[t] = acc;
        }
    }
}

// ---------- launch ----------

static inline size_t align_up(size_t v, size_t a) { return (v + a - 1) & ~(a - 1); }

extern "C" void kernel_launch(void* const* d_in, const int* in_sizes, int n_in, void* d_out,
                              int out_size, void* d_ws, size_t ws_size, hipStream_t stream) {
    const float* x = (const float*)d_in[0];
    const int* ei = (const int*)d_in[1];
    const float* W1 = (const float*)d_in[2];
    const float* b1 = (const float*)d_in[3];
    const float* W2 = (const float*)d_in[4];
    const float* b2 = (const float*)d_in[5];
    const float* gn_w = (const float*)d_in[6];
    const float* gn_b = (const float*)d_in[7];
    const float* gn_ms = (const float*)d_in[8];
    const float* ln_w = (const float*)d_in[9];
    const float* ln_b = (const float*)d_in[10];
    const float* fc_W = (const float*)d_in[11];
    const float* fc_b = (const float*)d_in[12];
    float* out = (float*)d_out;

    const int N = in_sizes[0] / 128;
    const int E = in_sizes[1] / 2;
    const int NB = (N + CHUNK - 1) / CHUNK;

    char* ws = (char*)d_ws;
    size_t off = 0;
    auto alloc = [&](size_t bytes) {
        char* p = ws + off;
        off = align_up(off + bytes, 256);
        return p;
    };
    int2* NI = (int2*)alloc((size_t)N * 8);
    float* dinv = (float*)alloc((size_t)N * 4);
    unsigned* bdata = (unsigned*)alloc((size_t)NB * CAP * 4);
    int* srcs = (int*)alloc((size_t)NB * CAP * 4);
    ushort* bufB = (ushort*)alloc((size_t)N * 64 * 2);
    ushort* wsw1 = (ushort*)alloc(128 * 64 * 2);
    ushort* wsw2 = (ushort*)alloc(64 * 64 * 2);
    char* T8 = (char*)alloc((size_t)N * 64 + 64);            // int8 table + zero row
    float* scales16 = (float*)alloc(((size_t)N / 16 + 2) * 4);  // per-16-row scale (~25KB)
    // ---- single contiguous zero region: [deg][sums][pooled][bcur][done] (prep zeroes) ----
    size_t zoff = off;
    int* deg = (int*)alloc((size_t)N * 4);          // global per-node degree (scatter fills)
    float* sums = (float*)alloc(256 * 4);
    unsigned* pooled = (unsigned*)alloc(64 * 4);
    int* bcur = (int*)alloc((size_t)(NB + 1) * 4);  // RELATIVE cursors, zeroed by prep
    unsigned* done = (unsigned*)alloc(4);
    size_t zlen = off - zoff;  // 256-aligned, divisible by 16

    // CSR build: fixed-capacity buckets; prep zeroes deg+zero-region (grid covers ~25.3K uint4)
    int nbB = (E + EPB - 1) / EPB;
    prep_kernel<<<128, 256, 0, stream>>>(W1, W2, wsw1, wsw2, (uint4*)(ws + zoff),
                                         (int)(zlen / 16), T8, scales16, N);
    bucket_scatter<<<nbB, 256, 0, stream>>>(ei, bcur, bdata, deg, E, NB);
    bucket_finish<<<NB, 256, 0, stream>>>(bdata, bcur, deg, NI, dinv, srcs, N);

    int nbMM = (N + 63) / 64;
    int nbAgg = 782;  // ~4 node-octets per wave (balanced grid-stride)
    size_t scb = ((size_t)(N >> 4) + 2) * 4;  // dynamic LDS for staged scales

    // Layer 1
    mm1_kernel<<<nbMM, 256, 0, stream>>>(x, wsw1, dinv, T8, scales16, N);
    agg_kernel<<<nbAgg, 256, scb, stream>>>(T8, scales16, NI, srcs, dinv, b1, bufB, sums, N);

    // Layer 2
    mm2_kernel<<<nbMM, 256, 0, stream>>>(bufB, wsw2, sums, gn_w, gn_b, gn_ms, ln_w, ln_b, dinv,
                                         T8, scales16, N);
    agg_kernel<<<nbAgg, 256, scb, stream>>>(T8, scales16, NI, srcs, dinv, b2, bufB,
                                            sums + 128, N);
    gnlnmax_final<<<512, 256, 0, stream>>>(bufB, sums + 128, gn_w, gn_b, gn_ms, ln_w, ln_b,
                                           pooled, done, fc_W, fc_b, out, N);
}

// Round 12
// 272.872 us; speedup vs baseline: 1.2146x; 1.2146x over previous
//
#include <hip/hip_runtime.h>
#include <hip/hip_bf16.h>

#define EPSV 1e-5f
#define CHUNK 256   // dst nodes per bucket (bucket = dst >> 8)
#define CAP 6144    // slots per bucket (mean 4096, +16 sigma + padding)
#define MAXNB 512   // supports N <= 131072
#define EPB 4096    // edges per block in bucket_scatter

typedef __attribute__((ext_vector_type(8))) short bf16x8;
typedef __attribute__((ext_vector_type(4))) float f32x4;

__device__ __forceinline__ ushort f2bf(float f) {
    union { float f; unsigned u; } c; c.f = f;
    unsigned u = c.u;
    return (ushort)((u + 0x7fffu + ((u >> 16) & 1u)) >> 16);
}
__device__ __forceinline__ float bf2f(ushort h) {
    union { unsigned u; float f; } c; c.u = ((unsigned)h) << 16;
    return c.f;
}
__device__ __forceinline__ float bflo(unsigned u) {
    union { unsigned u; float f; } c; c.u = u << 16;
    return c.f;
}
__device__ __forceinline__ float bfhi(unsigned u) {
    union { unsigned u; float f; } c; c.u = u & 0xFFFF0000u;
    return c.f;
}
// int8 row decode-accumulate: a[f] += sc * q[f]  (q packed 8x int8 in uint2)
__device__ __forceinline__ void accq(float* a, uint2 g, float sc) {
    a[0] += sc * (float)(signed char)(g.x & 0xFF);
    a[1] += sc * (float)(signed char)((g.x >> 8) & 0xFF);
    a[2] += sc * (float)(signed char)((g.x >> 16) & 0xFF);
    a[3] += sc * (float)(signed char)(g.x >> 24);
    a[4] += sc * (float)(signed char)(g.y & 0xFF);
    a[5] += sc * (float)(signed char)((g.y >> 8) & 0xFF);
    a[6] += sc * (float)(signed char)((g.y >> 16) & 0xFF);
    a[7] += sc * (float)(signed char)(g.y >> 24);
}

// ---------- prep: W swizzle + zeroing (zero region, table zero-row, tail scale) ----------
// W (k,n) -> wsw[((k>>3)*64 + n)*8 + (k&7)]
// Zeroed EVERY launch (re-poison safe); bcur is RELATIVE cursors for bucket_scatter.
// R11 lesson: NO global deg array — 1.6M scattered cross-XCD atomics cost +52us.

__global__ void prep_kernel(const float* __restrict__ W1, const float* __restrict__ W2,
                            ushort* __restrict__ wsw1, ushort* __restrict__ wsw2,
                            uint4* __restrict__ zr, int nz16, char* __restrict__ T8,
                            float* __restrict__ scales16, int N) {
    int t = blockIdx.x * blockDim.x + threadIdx.x;  // 48*256 = 12288
    if (t < 128 * 64) {
        int k = t >> 6, n = t & 63;
        wsw1[((k >> 3) * 64 + n) * 8 + (k & 7)] = f2bf(W1[t]);
    }
    if (t < 64 * 64) {
        int k = t >> 6, n = t & 63;
        wsw2[((k >> 3) * 64 + n) * 8 + (k & 7)] = f2bf(W2[t]);
    }
    if (t < nz16) zr[t] = make_uint4(0u, 0u, 0u, 0u);
    if (t < 4) reinterpret_cast<uint4*>(T8 + (size_t)N * 64)[t] = make_uint4(0u, 0u, 0u, 0u);
    if (t == 4) scales16[N >> 4] = 0.f;  // zero-row group scale
}

// ---------- bucket scatter: pack (src | dloc<<20) into fixed-cap bucket regions ----------
// R3 lesson: single-pass scatter into per-node slots costs 97MB of HBM writes (64B-line
// amplification). Bucket cursors fill lines sequentially. bcur RELATIVE (zeroed by prep).
// R10 form exactly (R11's fused global-deg atomics: +52us, reverted).

__global__ void __launch_bounds__(256) bucket_scatter(const int* __restrict__ ei,
                                                      int* __restrict__ bcur,
                                                      unsigned* __restrict__ bdata, int E,
                                                      int NB) {
    __shared__ int h[MAXNB];
    __shared__ int cur[MAXNB];
    int t = threadIdx.x;
    int base = blockIdx.x * EPB;
    int end = min(base + EPB, E);
    for (int b = t; b < NB; b += 256) h[b] = 0;
    __syncthreads();
    // hist pass (int4 over dst; E and EPB divisible by 4)
    for (int e = base + t * 4; e < end; e += 1024) {
        int4 d4 = *reinterpret_cast<const int4*>(&ei[E + e]);
        atomicAdd(&h[d4.x >> 8], 1);
        atomicAdd(&h[d4.y >> 8], 1);
        atomicAdd(&h[d4.z >> 8], 1);
        atomicAdd(&h[d4.w >> 8], 1);
    }
    __syncthreads();
    for (int b = t; b < NB; b += 256) {
        int c = h[b];
        cur[b] = c ? (atomicAdd(&bcur[b], c) + b * CAP) : 0;
    }
    __syncthreads();
    for (int e = base + t * 4; e < end; e += 1024) {
        int4 s4 = *reinterpret_cast<const int4*>(&ei[e]);
        int4 d4 = *reinterpret_cast<const int4*>(&ei[E + e]);
        int p0 = atomicAdd(&cur[d4.x >> 8], 1);
        bdata[p0] = (unsigned)s4.x | ((unsigned)(d4.x & 255) << 20);
        int p1 = atomicAdd(&cur[d4.y >> 8], 1);
        bdata[p1] = (unsigned)s4.y | ((unsigned)(d4.y & 255) << 20);
        int p2 = atomicAdd(&cur[d4.z >> 8], 1);
        bdata[p2] = (unsigned)s4.z | ((unsigned)(d4.z & 255) << 20);
        int p3 = atomicAdd(&cur[d4.w >> 8], 1);
        bdata[p3] = (unsigned)s4.w | ((unsigned)(d4.w & 255) << 20);
    }
}

// ---------- bucket finish v3: SINGLE bdata read (register-cached) ----------
// Each thread owns <=24 bucket entries (6 x uint4, statically indexed). Hist pass loads
// them once into registers + LDS-atomic hist (LOCAL atomics — R11 lesson); place pass
// reuses the registers. Eliminates the second 6.4MB global read of R10's finish.
// srcs holds src*8; lists padded to x4 with ZR (= N*8) entries.

__global__ void __launch_bounds__(256) bucket_finish(const unsigned* __restrict__ bdata,
                                                     const int* __restrict__ bcur,
                                                     int2* __restrict__ NI,
                                                     float* __restrict__ dinv,
                                                     int* __restrict__ srcs, int N) {
    __shared__ int h[CHUNK];
    __shared__ int cur[CHUNK];
    int t = threadIdx.x;
    int beg = blockIdx.x * CAP;
    int nedge = bcur[blockIdx.x];  // relative count
    int end4 = beg + (nedge & ~3);
    h[t] = 0;
    __syncthreads();
    uint4 myv[6];
    unsigned tailv = 0u;
#pragma unroll
    for (int it = 0; it < 6; it++) {
        int e = beg + t * 4 + it * 1024;
        if (e < end4) {
            uint4 v = *reinterpret_cast<const uint4*>(&bdata[e]);
            myv[it] = v;
            atomicAdd(&h[v.x >> 20], 1);
            atomicAdd(&h[v.y >> 20], 1);
            atomicAdd(&h[v.z >> 20], 1);
            atomicAdd(&h[v.w >> 20], 1);
        }
    }
    bool hasTail = (t < (nedge & 3));
    if (hasTail) {
        tailv = bdata[end4 + t];
        atomicAdd(&h[tailv >> 20], 1);
    }
    __syncthreads();
    int deg = h[t];
    int pc = (deg + 3) & ~3;
    cur[t] = pc;
    __syncthreads();
    for (int off = 1; off < 256; off <<= 1) {
        int x = (t >= off) ? cur[t - off] : 0;
        __syncthreads();
        cur[t] += x;
        __syncthreads();
    }
    int begp = beg + cur[t] - pc;  // padded start for this node's list
    int node = blockIdx.x * CHUNK + t;
    if (node < N) {
        NI[node] = make_int2(begp, pc);
        dinv[node] = rsqrtf((float)deg + 1.0f);
    }
    h[t] = begp;
    __syncthreads();
#pragma unroll
    for (int it = 0; it < 6; it++) {
        int e = beg + t * 4 + it * 1024;
        if (e < end4) {
            uint4 v = myv[it];
            int p0 = atomicAdd(&h[v.x >> 20], 1);
            srcs[p0] = (int)((v.x & 0xFFFFFu) << 3);  // src * 8 (uint2 row offset)
            int p1 = atomicAdd(&h[v.y >> 20], 1);
            srcs[p1] = (int)((v.y & 0xFFFFFu) << 3);
            int p2 = atomicAdd(&h[v.z >> 20], 1);
            srcs[p2] = (int)((v.z & 0xFFFFFu) << 3);
            int p3 = atomicAdd(&h[v.w >> 20], 1);
            srcs[p3] = (int)((v.w & 0xFFFFFu) << 3);
        }
    }
    if (hasTail) {
        int pos = atomicAdd(&h[tailv >> 20], 1);
        srcs[pos] = (int)((tailv & 0xFFFFFu) << 3);
    }
    __syncthreads();
    // pad fill: h[t] is now begp+deg
    int zr = N * 8;
    for (int k = h[t]; k < begp + pc; k++) srcs[k] = zr;
}

// ---------- int8 quantize epilogue (shared by mm1/mm2), PER-16-ROW scale ----------
// A warp covers exactly rows [gw*16, gw*16+16): one full-wave max reduce gives the
// group scale. scales16 = 25KB total (R9-verified numerics, absmax 0.03125 passed).

__device__ __forceinline__ void quant_store(const f32x4* accs, const float* dv, int rbase,
                                            int ml, int gw, char* __restrict__ T8,
                                            float* __restrict__ scales16, int N) {
    float m = 0.f;
#pragma unroll
    for (int reg = 0; reg < 4; reg++) {
        float mr = fmaxf(fmaxf(fabsf(accs[0][reg]), fabsf(accs[1][reg])),
                         fmaxf(fabsf(accs[2][reg]), fabsf(accs[3][reg])));
        m = fmaxf(m, mr * dv[reg]);  // dv=0 for masked rows -> no contribution
    }
    m = fmaxf(m, __shfl_xor(m, 1));
    m = fmaxf(m, __shfl_xor(m, 2));
    m = fmaxf(m, __shfl_xor(m, 4));
    m = fmaxf(m, __shfl_xor(m, 8));
    m = fmaxf(m, __shfl_xor(m, 16));
    m = fmaxf(m, __shfl_xor(m, 32));
    m = fmaxf(m, 1e-20f);
    float inv = 127.f / m;
    if ((threadIdx.x & 63) == 0) scales16[gw] = m * (1.f / 127.f);
#pragma unroll
    for (int reg = 0; reg < 4; reg++) {
        int r = rbase + reg;
        if (r < N) {
            float s = dv[reg] * inv;
#pragma unroll
            for (int ct = 0; ct < 4; ct++) {
                int qv = __float2int_rn(accs[ct][reg] * s);
                T8[(size_t)r * 64 + ct * 16 + ml] = (char)qv;
            }
        }
    }
}

// ---------- matmul1: T8[N,64](int8)+scales16 = quant(dinv[r] * (X[N,128](fp32) @ W1)) ----------

__global__ void __launch_bounds__(256) mm1_kernel(const float* __restrict__ X,
                                                  const ushort* __restrict__ wsw,
                                                  const float* __restrict__ dinv,
                                                  char* __restrict__ T8,
                                                  float* __restrict__ scales16, int N) {
    const int KO = 4;
    int w = threadIdx.x >> 6, lane = threadIdx.x & 63;
    int ml = lane & 15, q = lane >> 4;
    int row = blockIdx.x * 64 + w * 16 + ml;

    bf16x8 afrag[KO];
#pragma unroll
    for (int kk = 0; kk < KO; kk++) {
        float xv[8];
        if (row < N) {
            const float4* xp = reinterpret_cast<const float4*>(X + (size_t)row * 128 + kk * 32 + q * 8);
            float4 v0 = xp[0], v1 = xp[1];
            xv[0] = v0.x; xv[1] = v0.y; xv[2] = v0.z; xv[3] = v0.w;
            xv[4] = v1.x; xv[5] = v1.y; xv[6] = v1.z; xv[7] = v1.w;
        } else {
#pragma unroll
            for (int j = 0; j < 8; j++) xv[j] = 0.f;
        }
#pragma unroll
        for (int j = 0; j < 8; j++) afrag[kk][j] = (short)f2bf(xv[j]);
    }

    int rbase = blockIdx.x * 64 + w * 16 + q * 4;
    float dv[4];
#pragma unroll
    for (int reg = 0; reg < 4; reg++) {
        int r = rbase + reg;
        dv[reg] = (r < N) ? dinv[r] : 0.f;
    }

    const bf16x8* wp = reinterpret_cast<const bf16x8*>(wsw);
    f32x4 accs[4];
#pragma unroll
    for (int ct = 0; ct < 4; ct++) {
        f32x4 acc = {0.f, 0.f, 0.f, 0.f};
#pragma unroll
        for (int kk = 0; kk < KO; kk++) {
            bf16x8 b = wp[(kk * 4 + q) * 64 + ct * 16 + ml];
            acc = __builtin_amdgcn_mfma_f32_16x16x32_bf16(afrag[kk], b, acc, 0, 0, 0);
        }
        accs[ct] = acc;
    }
    quant_store(accs, dv, rbase, ml, blockIdx.x * 4 + w, T8, scales16, N);
}

// ---------- matmul2: fused GraphNorm+LayerNorm on A, then T8 = quant(dinv * (norm(A) @ W2)) ----------

__global__ void __launch_bounds__(256) mm2_kernel(
    const ushort* __restrict__ A2, const ushort* __restrict__ wsw,
    const float* __restrict__ sums, const float* __restrict__ gn_w,
    const float* __restrict__ gn_b, const float* __restrict__ gn_ms,
    const float* __restrict__ ln_w, const float* __restrict__ ln_b,
    const float* __restrict__ dinv, char* __restrict__ T8,
    float* __restrict__ scales16, int N) {
    __shared__ float sg[64], tg[64], lwv[64], lbv[64];
    int t = threadIdx.x;
    if (t < 64) {
        float invN = 1.0f / (float)N;
        float mean = sums[t] * invN;
        float m2 = sums[64 + t] * invN;
        float ms = gn_ms[t];
        float var = m2 - 2.f * ms * mean * mean + ms * ms * mean * mean;
        float s = gn_w[t] * rsqrtf(var + EPSV);
        sg[t] = s;
        tg[t] = gn_b[t] - s * ms * mean;
        lwv[t] = ln_w[t];
        lbv[t] = ln_b[t];
    }
    __syncthreads();

    int w = t >> 6, lane = t & 63;
    int ml = lane & 15, q = lane >> 4;
    int row = blockIdx.x * 64 + w * 16 + ml;

    float g[16];
#pragma unroll
    for (int kk = 0; kk < 2; kk++) {
        uint4 u = make_uint4(0, 0, 0, 0);
        if (row < N)
            u = *reinterpret_cast<const uint4*>(A2 + (size_t)row * 64 + kk * 32 + q * 8);
        unsigned uu[4] = {u.x, u.y, u.z, u.w};
#pragma unroll
        for (int p = 0; p < 4; p++) {
            int f0 = kk * 32 + q * 8 + 2 * p;
            g[kk * 8 + 2 * p] = sg[f0] * bflo(uu[p]) + tg[f0];
            g[kk * 8 + 2 * p + 1] = sg[f0 + 1] * bfhi(uu[p]) + tg[f0 + 1];
        }
    }
    float s1 = 0.f;
#pragma unroll
    for (int i = 0; i < 16; i++) s1 += g[i];
    s1 += __shfl_xor(s1, 16);
    s1 += __shfl_xor(s1, 32);
    float mu = s1 * (1.f / 64.f);
    float s2 = 0.f;
#pragma unroll
    for (int i = 0; i < 16; i++) {
        float c = g[i] - mu;
        s2 += c * c;
    }
    s2 += __shfl_xor(s2, 16);
    s2 += __shfl_xor(s2, 32);
    float rs = rsqrtf(s2 * (1.f / 64.f) + EPSV);

    bf16x8 afrag[2];
#pragma unroll
    for (int kk = 0; kk < 2; kk++) {
#pragma unroll
        for (int j = 0; j < 8; j++) {
            int f = kk * 32 + q * 8 + j;
            float y = lwv[f] * (g[kk * 8 + j] - mu) * rs + lbv[f];
            afrag[kk][j] = (short)f2bf(y);
        }
    }

    int rbase = blockIdx.x * 64 + w * 16 + q * 4;
    float dv[4];
#pragma unroll
    for (int reg = 0; reg < 4; reg++) {
        int r = rbase + reg;
        dv[reg] = (r < N) ? dinv[r] : 0.f;
    }

    const bf16x8* wp = reinterpret_cast<const bf16x8*>(wsw);
    f32x4 accs[4];
#pragma unroll
    for (int ct = 0; ct < 4; ct++) {
        f32x4 acc = {0.f, 0.f, 0.f, 0.f};
#pragma unroll
        for (int kk = 0; kk < 2; kk++) {
            bf16x8 b = wp[(kk * 4 + q) * 64 + ct * 16 + ml];
            acc = __builtin_amdgcn_mfma_f32_16x16x32_bf16(afrag[kk], b, acc, 0, 0, 0);
        }
        accs[ct] = acc;
    }
    quant_store(accs, dv, rbase, ml, blockIdx.x * 4 + w, T8, scales16, N);
}

// ---------- edge aggregation v12 (FINAL): int8 table + LDS-staged scales ----------
// agg is at the random-gather serve-rate ceiling (~34G line-requests/s chip-wide):
// five falsified theories — more waves (R1), deeper pipeline (R2), fewer bytes (R8),
// fewer misses (R9), fewer L1 txns (R10: -1.6us only). Do not touch further.

__global__ void __launch_bounds__(256) agg_kernel(
    const char* __restrict__ T8, const float* __restrict__ scales16,
    const int2* __restrict__ NI, const int* __restrict__ srcs,
    const float* __restrict__ dinv, const float* __restrict__ bias,
    ushort* __restrict__ out, float* __restrict__ sums, int N) {
    extern __shared__ float sc[];  // (N>>4)+1 floats, dynamic
    int t = threadIdx.x;
    int nsc = (N >> 4) + 1;
    for (int i = t; i < nsc; i += 256) sc[i] = scales16[i];
    __syncthreads();

    int lane = t & 63;
    int g = lane >> 3, fq = lane & 7;
    int wid = (blockIdx.x * blockDim.x + t) >> 6;
    int nw = (gridDim.x * blockDim.x) >> 6;
    const uint2* H2 = reinterpret_cast<const uint2*>(T8);
    uint4* O4 = reinterpret_cast<uint4*>(out);
    const int ZR = N * 8;
    float bb[8];
#pragma unroll
    for (int j = 0; j < 8; j++) bb[j] = bias[fq * 8 + j];
    float ps1[8] = {0, 0, 0, 0, 0, 0, 0, 0}, ps2[8] = {0, 0, 0, 0, 0, 0, 0, 0};

    for (int jo = wid; jo * 8 < N; jo += nw) {
        int node = jo * 8 + g;
        bool valid = node < N;
        int2 info = valid ? NI[node] : make_int2(0, 0);
        float di = valid ? dinv[node] : 0.f;
        int e = info.x, end = info.x + info.y;
        float a[8] = {0, 0, 0, 0, 0, 0, 0, 0};
        for (; e + 8 <= end; e += 8) {
            int4 i0 = *reinterpret_cast<const int4*>(&srcs[e]);
            int4 i1 = *reinterpret_cast<const int4*>(&srcs[e + 4]);
            uint2 g0 = H2[i0.x + fq];
            uint2 g1 = H2[i0.y + fq];
            uint2 g2 = H2[i0.z + fq];
            uint2 g3 = H2[i0.w + fq];
            uint2 g4 = H2[i1.x + fq];
            uint2 g5 = H2[i1.y + fq];
            uint2 g6 = H2[i1.z + fq];
            uint2 g7 = H2[i1.w + fq];
            float s0 = sc[i0.x >> 7];   // (src*8)>>7 = src>>4 ; LDS, not L1
            float s1 = sc[i0.y >> 7];
            float s2 = sc[i0.z >> 7];
            float s3 = sc[i0.w >> 7];
            float s4 = sc[i1.x >> 7];
            float s5 = sc[i1.y >> 7];
            float s6 = sc[i1.z >> 7];
            float s7 = sc[i1.w >> 7];
            accq(a, g0, s0); accq(a, g1, s1); accq(a, g2, s2); accq(a, g3, s3);
            accq(a, g4, s4); accq(a, g5, s5); accq(a, g6, s6); accq(a, g7, s7);
        }
        if (e < end) {  // remainder is exactly 4 (lists padded to x4)
            int4 i0 = *reinterpret_cast<const int4*>(&srcs[e]);
            uint2 g0 = H2[i0.x + fq];
            uint2 g1 = H2[i0.y + fq];
            uint2 g2 = H2[i0.z + fq];
            uint2 g3 = H2[i0.w + fq];
            float s0 = sc[i0.x >> 7];
            float s1 = sc[i0.y >> 7];
            float s2 = sc[i0.z >> 7];
            float s3 = sc[i0.w >> 7];
            accq(a, g0, s0); accq(a, g1, s1); accq(a, g2, s2); accq(a, g3, s3);
        }
        // self term: same di coefficient as neighbors -> fold into a[]
        uint2 us = H2[(valid ? node * 8 : ZR) + fq];
        float scs = sc[(valid ? node : N) >> 4];
        accq(a, us, scs);
        float vv[8];
#pragma unroll
        for (int j = 0; j < 8; j++) vv[j] = fmaxf(di * a[j] + bb[j], 0.f);
        if (valid) {
            uint4 o;
            o.x = (unsigned)f2bf(vv[0]) | ((unsigned)f2bf(vv[1]) << 16);
            o.y = (unsigned)f2bf(vv[2]) | ((unsigned)f2bf(vv[3]) << 16);
            o.z = (unsigned)f2bf(vv[4]) | ((unsigned)f2bf(vv[5]) << 16);
            o.w = (unsigned)f2bf(vv[6]) | ((unsigned)f2bf(vv[7]) << 16);
            O4[(size_t)node * 8 + fq] = o;
#pragma unroll
            for (int j = 0; j < 8; j++) {
                ps1[j] += vv[j];
                ps2[j] += vv[j] * vv[j];
            }
        }
    }

    // colstats: reduce across the 8 groups (same fq -> same features), stage in LDS
    __shared__ float red[4][128];
    int wv = t >> 6;
#pragma unroll
    for (int j = 0; j < 8; j++) {
        float s = ps1[j], q = ps2[j];
        s += __shfl_xor(s, 8); s += __shfl_xor(s, 16); s += __shfl_xor(s, 32);
        q += __shfl_xor(q, 8); q += __shfl_xor(q, 16); q += __shfl_xor(q, 32);
        if (g == 0) {
            red[wv][fq * 8 + j] = s;
            red[wv][64 + fq * 8 + j] = q;
        }
    }
    __syncthreads();
    if (t < 128) {
        float v = red[0][t] + red[1][t] + red[2][t] + red[3][t];
        atomicAdd(&sums[t], v);
    }
}

// ---------- layer-2 norms + max-pool + (last block) final FC ----------
// 8x8 layout (R5-verified): lane fq loads uint4 (8 features) of row jo*8+g; wave reads
// 1KB coalesced covering 8 rows/iter; LN reductions are 3-hop shfl within 8-lane group.

__device__ __forceinline__ unsigned fkey(float f) {
    unsigned u = __float_as_uint(f);
    return (u & 0x80000000u) ? ~u : (u | 0x80000000u);
}

__global__ void __launch_bounds__(256) gnlnmax_final(
    const ushort* __restrict__ A, const float* __restrict__ sums,
    const float* __restrict__ gn_w, const float* __restrict__ gn_b,
    const float* __restrict__ gn_ms, const float* __restrict__ ln_w,
    const float* __restrict__ ln_b, unsigned* __restrict__ pooled,
    unsigned* __restrict__ done, const float* __restrict__ fc_W,
    const float* __restrict__ fc_b, float* __restrict__ out, int N) {
    __shared__ float sg[64], tg[64];
    int t = threadIdx.x;
    if (t < 64) {
        float invN = 1.0f / (float)N;
        float mean = sums[t] * invN;
        float m2 = sums[64 + t] * invN;
        float ms = gn_ms[t];
        float var = m2 - 2.f * ms * mean * mean + ms * ms * mean * mean;
        float s = gn_w[t] * rsqrtf(var + EPSV);
        sg[t] = s;
        tg[t] = gn_b[t] - s * ms * mean;
    }
    __syncthreads();

    int lane = t & 63;
    int g = lane >> 3, fq = lane & 7;
    float sgv[8], tgv[8], lwv[8], lbv[8];
#pragma unroll
    for (int j = 0; j < 8; j++) {
        sgv[j] = sg[fq * 8 + j];
        tgv[j] = tg[fq * 8 + j];
        lwv[j] = ln_w[fq * 8 + j];
        lbv[j] = ln_b[fq * 8 + j];
    }

    int wid = (blockIdx.x * blockDim.x + t) >> 6;
    int nw = (gridDim.x * blockDim.x) >> 6;
    const uint4* A4 = reinterpret_cast<const uint4*>(A);
    float mx[8];
#pragma unroll
    for (int j = 0; j < 8; j++) mx[j] = -3.4e38f;

    for (int jo = wid; jo * 8 < N; jo += nw) {
        int row = jo * 8 + g;
        bool valid = row < N;
        uint4 u = A4[(size_t)(valid ? row : 0) * 8 + fq];
        float y[8];
        y[0] = sgv[0] * bflo(u.x) + tgv[0];
        y[1] = sgv[1] * bfhi(u.x) + tgv[1];
        y[2] = sgv[2] * bflo(u.y) + tgv[2];
        y[3] = sgv[3] * bfhi(u.y) + tgv[3];
        y[4] = sgv[4] * bflo(u.z) + tgv[4];
        y[5] = sgv[5] * bfhi(u.z) + tgv[5];
        y[6] = sgv[6] * bflo(u.w) + tgv[6];
        y[7] = sgv[7] * bfhi(u.w) + tgv[7];
        float s1 = 0.f;
#pragma unroll
        for (int j = 0; j < 8; j++) s1 += y[j];
        s1 += __shfl_xor(s1, 1);
        s1 += __shfl_xor(s1, 2);
        s1 += __shfl_xor(s1, 4);
        float mu = s1 * (1.f / 64.f);
        float s2 = 0.f;
#pragma unroll
        for (int j = 0; j < 8; j++) {
            float c = y[j] - mu;
            s2 += c * c;
        }
        s2 += __shfl_xor(s2, 1);
        s2 += __shfl_xor(s2, 2);
        s2 += __shfl_xor(s2, 4);
        float rs = rsqrtf(s2 * (1.f / 64.f) + EPSV);
        if (valid) {
#pragma unroll
            for (int j = 0; j < 8; j++)
                mx[j] = fmaxf(mx[j], lwv[j] * (y[j] - mu) * rs + lbv[j]);
        }
    }

    // reduce max across the 8 groups (same fq -> same features), stage in LDS
    __shared__ float red[4][64];
    int wv = t >> 6;
#pragma unroll
    for (int j = 0; j < 8; j++) {
        float m = mx[j];
        m = fmaxf(m, __shfl_xor(m, 8));
        m = fmaxf(m, __shfl_xor(m, 16));
        m = fmaxf(m, __shfl_xor(m, 32));
        if (g == 0) red[wv][fq * 8 + j] = m;
    }
    __syncthreads();
    if (t < 64) {
        float m = fmaxf(fmaxf(red[0][t], red[1][t]), fmaxf(red[2][t], red[3][t]));
        atomicMax(&pooled[t], fkey(m));
    }
    __syncthreads();  // all this block's atomicMax issued before the counter bump
    __shared__ int islast;
    if (t == 0) {
        __threadfence();  // publish our maxes
        unsigned old = atomicAdd(done, 1u);
        islast = (old == gridDim.x - 1);
    }
    __syncthreads();
    if (islast) {  // every other block fenced+counted -> their maxes are visible
        __shared__ float p[64];
        if (t < 64) {
            __threadfence();
            unsigned u = atomicAdd(&pooled[t], 0u);  // atomic RMW read bypasses stale caches
            p[t] = (u & 0x80000000u) ? __uint_as_float(u ^ 0x80000000u) : __uint_as_float(~u);
        }
        __syncthreads();
        if (t < 32) {
            float acc = fc_b[t];
#pragma unroll
            for (int f = 0; f < 64; f++) acc += p[f] * fc_W[f * 32 + t];
            out[t] = acc;
        }
    }
}

// ---------- launch ----------

static inline size_t align_up(size_t v, size_t a) { return (v + a - 1) & ~(a - 1); }

extern "C" void kernel_launch(void* const* d_in, const int* in_sizes, int n_in, void* d_out,
                              int out_size, void* d_ws, size_t ws_size, hipStream_t stream) {
    const float* x = (const float*)d_in[0];
    const int* ei = (const int*)d_in[1];
    const float* W1 = (const float*)d_in[2];
    const float* b1 = (const float*)d_in[3];
    const float* W2 = (const float*)d_in[4];
    const float* b2 = (const float*)d_in[5];
    const float* gn_w = (const float*)d_in[6];
    const float* gn_b = (const float*)d_in[7];
    const float* gn_ms = (const float*)d_in[8];
    const float* ln_w = (const float*)d_in[9];
    const float* ln_b = (const float*)d_in[10];
    const float* fc_W = (const float*)d_in[11];
    const float* fc_b = (const float*)d_in[12];
    float* out = (float*)d_out;

    const int N = in_sizes[0] / 128;
    const int E = in_sizes[1] / 2;
    const int NB = (N + CHUNK - 1) / CHUNK;

    char* ws = (char*)d_ws;
    size_t off = 0;
    auto alloc = [&](size_t bytes) {
        char* p = ws + off;
        off = align_up(off + bytes, 256);
        return p;
    };
    int2* NI = (int2*)alloc((size_t)N * 8);
    float* dinv = (float*)alloc((size_t)N * 4);
    unsigned* bdata = (unsigned*)alloc((size_t)NB * CAP * 4);
    int* srcs = (int*)alloc((size_t)NB * CAP * 4);
    ushort* bufB = (ushort*)alloc((size_t)N * 64 * 2);
    ushort* wsw1 = (ushort*)alloc(128 * 64 * 2);
    ushort* wsw2 = (ushort*)alloc(64 * 64 * 2);
    char* T8 = (char*)alloc((size_t)N * 64 + 64);            // int8 table + zero row
    float* scales16 = (float*)alloc(((size_t)N / 16 + 2) * 4);  // per-16-row scale (~25KB)
    // ---- single contiguous zero region: [sums][pooled][bcur][done] (prep zeroes) ----
    size_t zoff = off;
    float* sums = (float*)alloc(256 * 4);
    unsigned* pooled = (unsigned*)alloc(64 * 4);
    int* bcur = (int*)alloc((size_t)(NB + 1) * 4);  // RELATIVE cursors, zeroed by prep
    unsigned* done = (unsigned*)alloc(4);
    size_t zlen = off - zoff;  // 256-aligned, divisible by 16

    // CSR build: fixed-capacity buckets; prep also zeroes zero-region + table row N
    int nbB = (E + EPB - 1) / EPB;
    prep_kernel<<<48, 256, 0, stream>>>(W1, W2, wsw1, wsw2, (uint4*)(ws + zoff),
                                        (int)(zlen / 16), T8, scales16, N);
    bucket_scatter<<<nbB, 256, 0, stream>>>(ei, bcur, bdata, E, NB);
    bucket_finish<<<NB, 256, 0, stream>>>(bdata, bcur, NI, dinv, srcs, N);

    int nbMM = (N + 63) / 64;
    int nbAgg = 782;  // ~4 node-octets per wave (balanced grid-stride)
    size_t scb = ((size_t)(N >> 4) + 2) * 4;  // dynamic LDS for staged scales

    // Layer 1
    mm1_kernel<<<nbMM, 256, 0, stream>>>(x, wsw1, dinv, T8, scales16, N);
    agg_kernel<<<nbAgg, 256, scb, stream>>>(T8, scales16, NI, srcs, dinv, b1, bufB, sums, N);

    // Layer 2
    mm2_kernel<<<nbMM, 256, 0, stream>>>(bufB, wsw2, sums, gn_w, gn_b, gn_ms, ln_w, ln_b, dinv,
                                         T8, scales16, N);
    agg_kernel<<<nbAgg, 256, scb, stream>>>(T8, scales16, NI, srcs, dinv, b2, bufB,
                                            sums + 128, N);
    gnlnmax_final<<<512, 256, 0, stream>>>(bufB, sums + 128, gn_w, gn_b, gn_ms, ln_w, ln_b,
                                           pooled, done, fc_W, fc_b, out, N);
}